// Round 5
// baseline (733.148 us; speedup 1.0000x reference)
//
#include <hip/hip_runtime.h>
#include <math.h>

typedef unsigned short u16;
typedef float f32x2 __attribute__((ext_vector_type(2)));
typedef float f32x4 __attribute__((ext_vector_type(4)));
typedef __bf16 bf16x8 __attribute__((ext_vector_type(8)));
typedef unsigned short u16x4 __attribute__((ext_vector_type(4)));
typedef unsigned short u16x8 __attribute__((ext_vector_type(8)));

__device__ __forceinline__ float bf2f(u16 u) {
    union { float f; unsigned int i; } v; v.i = ((unsigned int)u) << 16; return v.f;
}
__device__ __forceinline__ u16 f2bf(float f) {
    union { float f; unsigned int i; } v; v.f = f;
    unsigned int r = v.i + 0x7fffu + ((v.i >> 16) & 1u);
    return (u16)(r >> 16);
}
// lane^1 value exchange via DPP quad_perm [1,0,3,2] (pure VALU, no LDS pipe)
__device__ __forceinline__ float dpp_swap1(float v) {
    union { float f; int i; } a, b; a.f = v;
    b.i = __builtin_amdgcn_update_dpp(0, a.i, 0xB1, 0xF, 0xF, true);
    return b.f;
}
__device__ __forceinline__ unsigned int pack2(float lo, float hi) {
    return (unsigned int)f2bf(lo) | ((unsigned int)f2bf(hi) << 16);
}

// async global->LDS, 16B per lane. LDS dest is wave-uniform base + lane*16.
__device__ __forceinline__ void gll(const u16* g, u16* l) {
    __builtin_amdgcn_global_load_lds((const __attribute__((address_space(1))) void*)g,
                                     (__attribute__((address_space(3))) void*)l, 16, 0, 0);
}

// ---------------- epilogue functors (operator() form, for gemm128) ----------------
struct EpiBF16 {            // bf16 store with batch stride
    u16* C; long zs; int ldc;
    __device__ void operator()(int z, int m, int n, float v) const {
        C[(long)z * zs + (long)m * ldc + n] = f2bf(v);
    }
};
struct EpiScale {           // scores: scale then bf16 store (tier B/C)
    u16* C; long zs; int ldc; float s;
    __device__ void operator()(int z, int m, int n, float v) const {
        C[(long)z * zs + (long)m * ldc + n] = f2bf(v * s);
    }
};
struct EpiAcc {             // x2 += v  (fp32, 512-wide rows)
    float* x2;
    __device__ void operator()(int z, int m, int n, float v) const {
        x2[(long)m * 512 + n] += v;
    }
};
struct EpiBias16 {          // v + fp32 bias -> bf16
    u16* C; const float* bias;
    __device__ void operator()(int z, int m, int n, float v) const {
        C[(long)m * 512 + n] = f2bf(v + bias[n]);
    }
};
struct EpiGL {              // split N=1024 into g (n<512) and l, with biases
    u16* g; u16* l; const float* bg; const float* bl;
    __device__ void operator()(int z, int m, int n, float v) const {
        if (n < 512) g[(long)m * 512 + n] = f2bf(v + bg[n]);
        else         l[(long)m * 512 + n - 512] = f2bf(v + bl[n - 512]);
    }
};
struct EpiCtxMul {          // ctx: rcp(rowsum), even-lane packed u32 store
    u16* C; const float* rs;    // rs[z*1024+m] = rowsum
    __device__ void operator()(int z, int m, int n, float v) const {
        float r = __builtin_amdgcn_rcpf(rs[(long)z * 1024 + m]);
        float o = v * r;
        float po = dpp_swap1(o);          // partner column's scaled value
        if (!(n & 1))
            *(unsigned int*)(C + (long)z * 524288 + (long)m * 512 + n) = pack2(o, po);
    }
};

// ---------------- epilogue functors (elem/row form, for gemm256) ----------------
struct EpiScores {          // C = exp(sscale*acc), even-lane packed; rowsum -> atomics
    u16* C; float* rs; float sscale;
    __device__ float elem(int z, int m, int n, float v) const {
        float e = __expf(v * sscale);
        float pe = dpp_swap1(e);
        if (!(n & 1))
            *(unsigned int*)(C + (long)z * 1048576 + (long)m * 1024 + n) = pack2(e, pe);
        return e;
    }
    __device__ void row(int z, int m, float p, int l15) const {
        p += __shfl_xor(p, 1, 64); p += __shfl_xor(p, 2, 64);
        p += __shfl_xor(p, 4, 64); p += __shfl_xor(p, 8, 64);
        if (l15 == 0) atomicAdd(rs + (long)z * 1024 + m, p);
    }
};
struct EpiPart {            // split-K fp32 partials, even-lane f32x2 store (no atomics)
    float* p;               // slice z at z*4194304
    __device__ float elem(int z, int m, int n, float v) const {
        float pv = dpp_swap1(v);
        if (!(n & 1)) {
            f32x2 o; o[0] = v; o[1] = pv;
            *(f32x2*)(p + (long)z * 4194304 + (long)m * 512 + n) = o;
        }
        return 0.f;
    }
    __device__ void row(int, int, float, int) const {}
};

// ======================================================================
// shared 8-phase machinery (gemm256 family)
// ======================================================================
#define RDA(S, I) (*(const bf16x8*)(lds + (S) * 8192 + (I) * 512 + aro))
#define RDB(S, J) (*(const bf16x8*)(lds + (S) * 8192 + (J) * 512 + bro))
#define MFMA_PH(JP) do { \
    __builtin_amdgcn_s_barrier(); \
    asm volatile("s_waitcnt lgkmcnt(0)" ::: "memory"); \
    __builtin_amdgcn_sched_barrier(0); \
    __builtin_amdgcn_s_setprio(1); \
    _Pragma("unroll") \
    for (int i_ = 0; i_ < 8; i_++) { \
        acc[i_][2*(JP)]   = __builtin_amdgcn_mfma_f32_16x16x32_bf16(aF[i_], bF[0], acc[i_][2*(JP)], 0, 0, 0); \
        acc[i_][2*(JP)+1] = __builtin_amdgcn_mfma_f32_16x16x32_bf16(aF[i_], bF[1], acc[i_][2*(JP)+1], 0, 0, 0); \
    } \
    __builtin_amdgcn_s_setprio(0); \
} while (0)

// ======================================================================
// gemm256_qkv: PERSISTENT fused qk+v kernel. 1536 tiles (1024 qk + 512 vT),
// 256 blocks x 6 tiles; 3-half-tile stage-ahead crosses tile boundaries.
// Epilogues use even-lane pair packing: even lane computes BOTH outputs of
// its (n, n^1) pair (partner raw value via DPP) -> 1 float2 cs load + 1 u32
// store per pair. Halves epilogue VMEM ops (vmcnt counts stores: shorter
// drain before next tile's counted waits).
// ======================================================================
__launch_bounds__(512, 2)
__global__ void gemm256_qkv(const u16* __restrict__ xnb, const u16* __restrict__ Wqkv,
                            u16* __restrict__ q, u16* __restrict__ k, u16* __restrict__ vT,
                            const float* __restrict__ csT) {
    __shared__ __align__(16) u16 lds[65536];
    const int t = threadIdx.x;
    const int lane = t & 63, wave = t >> 6;
    const int wr = wave >> 2, wc = wave & 3;
    const int l15 = lane & 15, quad = lane >> 4;
    const int sr = t >> 2;
    const int scw = ((t & 3) ^ ((t >> 3) & 3)) * 8;
    u16* lA0 = lds + wave * 512 + lane * 8;
    u16* lB0 = lds + 32768 + wave * 512 + lane * 8;
    const int ap = (quad ^ ((l15 >> 1) & 3)) * 8;
    const int aro = (wr * 128 + l15) * 32 + ap;
    const int bro = 32768 + (wc * 64 + l15) * 32 + ap;
    const int bid = blockIdx.x;
    const bool evn = !(l15 & 1);

    const u16 *curA, *curB, *nxtA, *nxtB;
    int cm0, cn0, cz, cmode, nm0, nn0, nz, nmode;
    auto decode = [&](int tid, const u16*& A_, const u16*& B_,
                      int& m0_, int& n0_, int& z_, int& md_) {
        if (tid > 1535) tid = 1535;
        if (tid < 1024) {               // qk: A=xn rows, B=W rows; z 0..15
            md_ = 0; z_ = tid & 15; int rem = tid >> 4;
            m0_ = (rem >> 1) << 8; n0_ = (rem & 1) << 8;
            A_ = xnb + (long)(m0_ + sr) * 512 + scw;
            B_ = Wqkv + z_ * 262144 + (long)(n0_ + sr) * 512 + scw;
        } else {                        // v transposed: A=Wv, B=xn; z 0..7
            int v = tid - 1024; md_ = 1; z_ = v & 7; int rem = v >> 3;
            m0_ = (rem & 1) << 8; n0_ = (rem >> 1) << 8;
            A_ = Wqkv + 4194304 + z_ * 262144 + (long)(m0_ + sr) * 512 + scw;
            B_ = xnb + (long)(n0_ + sr) * 512 + scw;
        }
    };
    decode(bid, curA, curB, cm0, cn0, cz, cmode);
    decode(bid + 256, nxtA, nxtB, nm0, nn0, nz, nmode);

    auto STGA = [&](int s) {
        const u16* base = (s < 16) ? curA : nxtA;
        int c = (s < 16) ? s : s - 16;
        u16* d = lA0 + (s & 3) * 8192;
        const u16* src = base + c * 32;
        gll(src, d); gll(src + 65536, d + 4096);
    };
    auto STGB = [&](int s) {
        const u16* base = (s < 16) ? curB : nxtB;
        int c = (s < 16) ? s : s - 16;
        u16* d = lB0 + (s & 3) * 8192;
        const u16* src = base + c * 32;
        gll(src, d); gll(src + 65536, d + 4096);
    };

    STGA(0); STGB(0); STGA(1); STGB(1); STGA(2); STGB(2);
    asm volatile("s_waitcnt vmcnt(4)" ::: "memory");
    __builtin_amdgcn_s_barrier();

    for (int j = 0; j < 6; ++j) {
        f32x4 acc[8][4] = {};
        #pragma unroll
        for (int it = 0; it < 4; ++it) {
            const int sh = 3 + it * 4;
            bf16x8 aF[8], bF[2];
            #pragma unroll
            for (int i = 0; i < 8; i++) aF[i] = RDA(0, i);
            bF[0] = RDB(0, 0); bF[1] = RDB(0, 1);
            STGA(sh);
            MFMA_PH(0);
            __builtin_amdgcn_s_barrier();
            bF[0] = RDB(0, 2); bF[1] = RDB(0, 3);
            STGB(sh);
            MFMA_PH(1);
            __builtin_amdgcn_s_barrier();
            #pragma unroll
            for (int i = 0; i < 8; i++) aF[i] = RDA(1, i);
            bF[0] = RDB(1, 0); bF[1] = RDB(1, 1);
            STGA(sh + 1);
            MFMA_PH(0);
            __builtin_amdgcn_s_barrier();
            bF[0] = RDB(1, 2); bF[1] = RDB(1, 3);
            STGB(sh + 1);
            MFMA_PH(1);
            asm volatile("s_waitcnt vmcnt(4)" ::: "memory");
            __builtin_amdgcn_s_barrier();
            #pragma unroll
            for (int i = 0; i < 8; i++) aF[i] = RDA(2, i);
            bF[0] = RDB(2, 0); bF[1] = RDB(2, 1);
            STGA(sh + 2);
            MFMA_PH(0);
            __builtin_amdgcn_s_barrier();
            bF[0] = RDB(2, 2); bF[1] = RDB(2, 3);
            STGB(sh + 2);
            MFMA_PH(1);
            __builtin_amdgcn_s_barrier();
            #pragma unroll
            for (int i = 0; i < 8; i++) aF[i] = RDA(3, i);
            bF[0] = RDB(3, 0); bF[1] = RDB(3, 1);
            STGA(sh + 3);
            MFMA_PH(0);
            __builtin_amdgcn_s_barrier();
            bF[0] = RDB(3, 2); bF[1] = RDB(3, 3);
            STGB(sh + 3);
            MFMA_PH(1);
            asm volatile("s_waitcnt vmcnt(4)" ::: "memory");
            __builtin_amdgcn_s_barrier();
        }
        // ---- epilogue for cur tile (even-lane pair packing)
        if (cmode == 0) {
            u16* dst = ((cz >= 8) ? k : q) + ((long)(cz & 7) << 22);
            #pragma unroll
            for (int i = 0; i < 8; i++)
                #pragma unroll
                for (int r = 0; r < 4; r++) {
                    int m = cm0 + wr * 128 + i * 16 + quad * 4 + r;
                    const float* cs = csT + (long)(m & 1023) * 512;
                    #pragma unroll
                    for (int jj = 0; jj < 4; jj++) {
                        int n = cn0 + wc * 64 + jj * 16 + l15;
                        float val = acc[i][jj][r];
                        float pv = dpp_swap1(val);
                        if (evn) {
                            // n even: cs pair at cs + n ((n>>1)*2 == n)
                            f32x2 c2 = *(const f32x2*)(cs + n);
                            float oe = val * c2[0] + pv * c2[1];   // te*c + to*s
                            float oo = pv * c2[0] - val * c2[1];   // to*c - te*s
                            *(unsigned int*)(dst + (long)m * 512 + n) = pack2(oe, oo);
                        }
                    }
                }
        } else {
            #pragma unroll
            for (int i = 0; i < 8; i++)
                #pragma unroll
                for (int r = 0; r < 4; r++) {
                    int m = cm0 + wr * 128 + i * 16 + quad * 4 + r;     // feature d
                    #pragma unroll
                    for (int jj = 0; jj < 4; jj++) {
                        int n = cn0 + wc * 64 + jj * 16 + l15;           // token
                        float val = acc[i][jj][r];
                        float pv = dpp_swap1(val);
                        if (evn)
                            *(unsigned int*)(vT + ((long)cz << 22) + ((long)(n >> 10) << 19)
                                             + ((long)m << 10) + (n & 1023)) = pack2(val, pv);
                    }
                }
        }
        curA = nxtA; curB = nxtB; cm0 = nm0; cn0 = nn0; cz = nz; cmode = nmode;
        decode(bid + (j + 2) * 256, nxtA, nxtB, nm0, nn0, nz, nmode);
    }
    asm volatile("s_waitcnt vmcnt(0)" ::: "memory");
}

// ======================================================================
// gemm256: generic 256x256 8-phase kernel (scores, Wo split-K)
// ======================================================================
template <class Epi>
__launch_bounds__(512, 2)
__global__ void gemm256(const u16* __restrict__ A, const u16* __restrict__ B,
                        int nkh, int kssh, int lda, int ldb,
                        long aBatch, long bBatch, long aSeg, long bSeg, Epi epi) {
    __shared__ __align__(16) u16 lds[65536];    // 128 KiB: A [4][8192], B at +32768
    const int t = threadIdx.x;
    const int lane = t & 63, wave = t >> 6;
    const int wr = wave >> 2, wc = wave & 3;
    const int l15 = lane & 15, quad = lane >> 4;
    const int m0 = blockIdx.x * 256, n0 = blockIdx.y * 256;
    const int z = blockIdx.z;
    const int sr = t >> 2;                               // 0..127
    const int scw = ((t & 3) ^ ((t >> 3) & 3)) * 8;      // pre-swizzled col block
    const u16* gA = A + (long)z * aBatch + (long)(m0 + sr) * lda + scw;
    const u16* gB = B + (long)z * bBatch + (long)(n0 + sr) * ldb + scw;
    const long a128 = 128L * lda, b128 = 128L * ldb;
    u16* lA0 = lds + wave * 512 + lane * 8;
    u16* lB0 = lds + 32768 + wave * 512 + lane * 8;
    const int kmask = (1 << kssh) - 1;

    auto STA = [&](int shp) {
        int c = shp < nkh ? shp : nkh - 1;               // tail clamp (data unused)
        const u16* s = gA + (long)(c >> kssh) * aSeg + (c & kmask) * 32;
        u16* d = lA0 + (shp & 3) * 8192;
        gll(s, d); gll(s + a128, d + 4096);
    };
    auto STB = [&](int shp) {
        int c = shp < nkh ? shp : nkh - 1;
        const u16* s = gB + (long)(c >> kssh) * bSeg + (c & kmask) * 32;
        u16* d = lB0 + (shp & 3) * 8192;
        gll(s, d); gll(s + b128, d + 4096);
    };

    const int ap = (quad ^ ((l15 >> 1) & 3)) * 8;
    const int aro = (wr * 128 + l15) * 32 + ap;
    const int bro = 32768 + (wc * 64 + l15) * 32 + ap;
    f32x4 acc[8][4] = {};

    STA(0); STB(0); STA(1); STB(1); STA(2); STB(2);
    asm volatile("s_waitcnt vmcnt(4)" ::: "memory");
    __builtin_amdgcn_s_barrier();

    const int niter = nkh >> 2;                          // K/128
    int sh = 3;
    for (int it = 0; it < niter; it++) {
        bf16x8 aF[8], bF[2];
        #pragma unroll
        for (int i = 0; i < 8; i++) aF[i] = RDA(0, i);
        bF[0] = RDB(0, 0); bF[1] = RDB(0, 1);
        STA(sh);
        MFMA_PH(0);
        __builtin_amdgcn_s_barrier();
        bF[0] = RDB(0, 2); bF[1] = RDB(0, 3);
        STB(sh);
        MFMA_PH(1);
        __builtin_amdgcn_s_barrier();
        #pragma unroll
        for (int i = 0; i < 8; i++) aF[i] = RDA(1, i);
        bF[0] = RDB(1, 0); bF[1] = RDB(1, 1);
        STA(sh + 1);
        MFMA_PH(0);
        __builtin_amdgcn_s_barrier();
        bF[0] = RDB(1, 2); bF[1] = RDB(1, 3);
        STB(sh + 1);
        MFMA_PH(1);
        asm volatile("s_waitcnt vmcnt(4)" ::: "memory");
        __builtin_amdgcn_s_barrier();
        #pragma unroll
        for (int i = 0; i < 8; i++) aF[i] = RDA(2, i);
        bF[0] = RDB(2, 0); bF[1] = RDB(2, 1);
        STA(sh + 2);
        MFMA_PH(0);
        __builtin_amdgcn_s_barrier();
        bF[0] = RDB(2, 2); bF[1] = RDB(2, 3);
        STB(sh + 2);
        MFMA_PH(1);
        __builtin_amdgcn_s_barrier();
        #pragma unroll
        for (int i = 0; i < 8; i++) aF[i] = RDA(3, i);
        bF[0] = RDB(3, 0); bF[1] = RDB(3, 1);
        STA(sh + 3);
        MFMA_PH(0);
        __builtin_amdgcn_s_barrier();
        bF[0] = RDB(3, 2); bF[1] = RDB(3, 3);
        STB(sh + 3);
        MFMA_PH(1);
        asm volatile("s_waitcnt vmcnt(4)" ::: "memory");
        __builtin_amdgcn_s_barrier();
        sh += 4;
    }
    asm volatile("s_waitcnt vmcnt(0)" ::: "memory");

    #pragma unroll
    for (int i = 0; i < 8; i++)
        #pragma unroll
        for (int r = 0; r < 4; r++) {
            int m = m0 + wr * 128 + i * 16 + quad * 4 + r;
            float p = 0.f;
            #pragma unroll
            for (int j = 0; j < 4; j++)
                p += epi.elem(z, m, n0 + wc * 64 + j * 16 + l15, acc[i][j][r]);
            epi.row(z, m, p, l15);
        }
}
#undef RDA
#undef RDB
#undef MFMA_PH

// ------- GEMM 128x128 tile, BK=64. 32 KiB LDS -> 4 blocks/CU.
template <class Epi>
__launch_bounds__(256, 4)
__global__ void gemm128(const u16* __restrict__ A, const u16* __restrict__ B,
                        int Kseg, int nSeg, int lda, int ldb,
                        long aBatch, long bBatch, long aSeg, Epi epi) {
    __shared__ __align__(16) u16 sA[8192];   // 128 x 64
    __shared__ __align__(16) u16 sB[8192];
    const int t = threadIdx.x;
    const int lane = t & 63, wave = t >> 6;
    const int wr = wave >> 1, wc = wave & 1;
    const int l15 = lane & 15, quad = lane >> 4;
    const int m0 = blockIdx.x * 128, n0 = blockIdx.y * 128;
    const int sr = t >> 2;
    const int scw = ((t & 3) ^ ((t >> 3) & 3)) * 8;
    const u16* gA = A + (long)blockIdx.z * aBatch + (long)(m0 + sr) * lda + scw;
    const u16* gB = B + (long)blockIdx.z * bBatch + (long)(n0 + sr) * ldb + scw;
    const long a2 = 64L * lda, b2 = 64L * ldb;
    u16* lA = sA + wave * 512 + lane * 8;
    u16* lB = sB + wave * 512 + lane * 8;
    const int ap = (quad ^ ((l15 >> 1) & 3)) * 8;
    const int ab = (wr * 64 + l15) * 32 + ap;
    const int bb = (wc * 64 + l15) * 32 + ap;
    f32x4 acc[4][4] = {};
    for (int s = 0; s < nSeg; s++) {
        const u16* gAs = gA + (long)s * aSeg;
        const u16* gBs = gB + s * Kseg;
        for (int k0 = 0; k0 < Kseg; k0 += 64) {
            gll(gAs + k0, lA);             gll(gAs + k0 + a2, lA + 2048);
            gll(gBs + k0, lB);             gll(gBs + k0 + b2, lB + 2048);
            gll(gAs + k0 + 32, lA + 4096); gll(gAs + k0 + 32 + a2, lA + 6144);
            gll(gBs + k0 + 32, lB + 4096); gll(gBs + k0 + 32 + b2, lB + 6144);
            __syncthreads();
            #pragma unroll
            for (int half = 0; half < 2; half++) {
                bf16x8 aF[4], bF[4];
                #pragma unroll
                for (int i = 0; i < 4; i++) aF[i] = *(const bf16x8*)(sA + half * 4096 + ab + i * 512);
                #pragma unroll
                for (int j = 0; j < 4; j++) bF[j] = *(const bf16x8*)(sB + half * 4096 + bb + j * 512);
                #pragma unroll
                for (int i = 0; i < 4; i++)
                    #pragma unroll
                    for (int j = 0; j < 4; j++)
                        acc[i][j] = __builtin_amdgcn_mfma_f32_16x16x32_bf16(aF[i], bF[j], acc[i][j], 0, 0, 0);
            }
            __syncthreads();
        }
    }
    #pragma unroll
    for (int i = 0; i < 4; i++)
        #pragma unroll
        for (int j = 0; j < 4; j++)
            #pragma unroll
            for (int r = 0; r < 4; r++)
                epi(blockIdx.z, m0 + wr * 64 + i * 16 + quad * 4 + r,
                    n0 + wc * 64 + j * 16 + l15, acc[i][j][r]);
}

// ---------------- reductions / elementwise ----------------
__device__ __forceinline__ float waveSum(float v) {
    #pragma unroll
    for (int o = 32; o > 0; o >>= 1) v += __shfl_down(v, o, 64);
    return v;
}
__device__ __forceinline__ float invFromPart(const float* part, int b) {
    float s = part[b * 64 + (threadIdx.x & 63)];
    s = waveSum(s);
    s = __shfl(s, 0, 64);
    return sqrtf(524288.0f / s);
}

__global__ void sumsq_f32(const float* __restrict__ x, float* __restrict__ part) {
    __shared__ float tmp[4];
    long base = (long)blockIdx.x * 524288 + (long)blockIdx.y * 8192;
    float s = 0.f;
    for (int i = threadIdx.x * 4; i < 8192; i += 1024) {
        f32x4 v = *(const f32x4*)(x + base + i);
        s += v[0] * v[0] + v[1] * v[1] + v[2] * v[2] + v[3] * v[3];
    }
    s = waveSum(s);
    if ((threadIdx.x & 63) == 0) tmp[threadIdx.x >> 6] = s;
    __syncthreads();
    if (threadIdx.x == 0) part[blockIdx.x * 64 + blockIdx.y] = tmp[0] + tmp[1] + tmp[2] + tmp[3];
}
// x2 += sum of 4 Wo split-K partials; fused sumsq of result
__global__ void combine_x2(float* __restrict__ x2, const float* __restrict__ p,
                           float* __restrict__ part) {
    __shared__ float tmp[4];
    long base = (long)blockIdx.x * 524288 + (long)blockIdx.y * 8192;
    float s = 0.f;
    for (int i = threadIdx.x * 4; i < 8192; i += 1024) {
        f32x4 v = *(const f32x4*)(x2 + base + i);
        v = v + *(const f32x4*)(p + base + i);
        v = v + *(const f32x4*)(p + 4194304 + base + i);
        v = v + *(const f32x4*)(p + 8388608 + base + i);
        v = v + *(const f32x4*)(p + 12582912 + base + i);
        *(f32x4*)(x2 + base + i) = v;
        s += v[0] * v[0] + v[1] * v[1] + v[2] * v[2] + v[3] * v[3];
    }
    s = waveSum(s);
    if ((threadIdx.x & 63) == 0) tmp[threadIdx.x >> 6] = s;
    __syncthreads();
    if (threadIdx.x == 0) part[blockIdx.x * 64 + blockIdx.y] = tmp[0] + tmp[1] + tmp[2] + tmp[3];
}
__global__ void finalize_inv(const float* __restrict__ part, float* __restrict__ inv) {
    float s = part[blockIdx.x * 64 + threadIdx.x];
    s = waveSum(s);
    if (threadIdx.x == 0) inv[blockIdx.x] = sqrtf(524288.0f / s);  // 1/ff_rms
}
// tier A vectorized (x4) elementwise
__global__ void rmsnorm1f_a(const float* __restrict__ x, const float* __restrict__ scale,
                            const float* __restrict__ part, const float* __restrict__ bo,
                            u16* __restrict__ xnb, float* __restrict__ x2) {
    long i = ((long)blockIdx.x * 256 + threadIdx.x) * 4;     // grid 4096
    int b = (int)(i >> 19);
    float inv = invFromPart(part, b);
    f32x4 xv = *(const f32x4*)(x + i);
    f32x4 sv = *(const f32x4*)(scale + (int)(i & 524287));
    f32x4 bv = *(const f32x4*)(bo + (int)(i & 511));
    f32x4 v; u16x4 o;
    #pragma unroll
    for (int j = 0; j < 4; j++) { v[j] = xv[j] * inv * sv[j]; o[j] = f2bf(v[j]); }
    *(u16x4*)(xnb + i) = o;
    *(f32x4*)(x2 + i) = v + bv;
}
__global__ void rmsnorm2_a(const float* __restrict__ x2, const float* __restrict__ scale,
                           const float* __restrict__ part, u16* __restrict__ x3b) {
    long i = ((long)blockIdx.x * 256 + threadIdx.x) * 4;
    int b = (int)(i >> 19);
    float inv = invFromPart(part, b);
    f32x4 xv = *(const f32x4*)(x2 + i);
    f32x4 sv = *(const f32x4*)(scale + (int)(i & 524287));
    u16x4 o;
    #pragma unroll
    for (int j = 0; j < 4; j++) o[j] = f2bf(xv[j] * inv * sv[j]);
    *(u16x4*)(x3b + i) = o;
}
__global__ void final_out_a(const float* __restrict__ x2, const float* __restrict__ scale,
                            const float* __restrict__ part, const u16* __restrict__ g,
                            const u16* __restrict__ l, const float* __restrict__ beta,
                            float* __restrict__ out) {
    long i = ((long)blockIdx.x * 256 + threadIdx.x) * 4;
    int b = (int)(i >> 19);
    float inv2 = invFromPart(part, b);
    float bta = beta[0];
    f32x4 xv = *(const f32x4*)(x2 + i);
    f32x4 sv = *(const f32x4*)(scale + (int)(i & 524287));
    u16x4 gv4 = *(const u16x4*)(g + i);
    u16x4 lv4 = *(const u16x4*)(l + i);
    f32x4 o;
    #pragma unroll
    for (int j = 0; j < 4; j++) {
        float x3 = xv[j] * inv2 * sv[j];
        float gv = bf2f(gv4[j]), lv = bf2f(lv4[j]);
        float sw = gv / (1.0f + __expf(-bta * gv));
        o[j] = x3 + sw * lv;
    }
    *(f32x4*)(out + i) = o;
}
// tier B/C versions
__global__ void rmsnorm1f(const float* __restrict__ x, const float* __restrict__ scale,
                          const float* __restrict__ inv, const float* __restrict__ bo,
                          u16* __restrict__ xnb, float* __restrict__ x2) {
    long i = (long)blockIdx.x * 256 + threadIdx.x;
    int b = (int)(i >> 19), md = (int)(i & 524287);
    float v = x[i] * inv[b] * scale[md];
    xnb[i] = f2bf(v);
    x2[i] = v + bo[i & 511];
}
__global__ void rmsnorm2(const float* __restrict__ x2, const float* __restrict__ scale,
                         const float* __restrict__ inv, u16* __restrict__ x3b) {
    long i = (long)blockIdx.x * 256 + threadIdx.x;
    int b = (int)(i >> 19), md = (int)(i & 524287);
    x3b[i] = f2bf(x2[i] * inv[b] * scale[md]);
}
__global__ void final_out(const float* __restrict__ x2, const float* __restrict__ scale,
                          const float* __restrict__ inv2, const u16* __restrict__ g,
                          const u16* __restrict__ l, const float* __restrict__ beta,
                          float* __restrict__ out) {
    long i = (long)blockIdx.x * 256 + threadIdx.x;
    int b = (int)(i >> 19), md = (int)(i & 524287);
    float x3 = x2[i] * inv2[b] * scale[md];
    float gv = bf2f(g[i]), lv = bf2f(l[i]);
    float bta = beta[0];
    float sw = gv / (1.0f + expf(-bta * gv));
    out[i] = x3 + sw * lv;
}
__global__ void rope_tables_a(float* __restrict__ csT, float* __restrict__ rowsum) {
    int i = blockIdx.x * 256 + threadIdx.x;      // 262144
    int m = i >> 8, j = i & 255;
    float theta = powf(10000.0f, -2.0f * ((float)j - 1.0f) / 512.0f);
    float ang = (float)m * theta;
    csT[2 * i] = cosf(ang); csT[2 * i + 1] = sinf(ang);
    if (i < 65536) rowsum[i] = 0.f;
}
__global__ void rope_tables(float* __restrict__ cosT, float* __restrict__ sinT) {
    int i = blockIdx.x * 256 + threadIdx.x;      // 1024*256
    int m = i >> 8, j = i & 255;
    float theta = powf(10000.0f, -2.0f * ((float)j - 1.0f) / 512.0f);
    float ang = (float)m * theta;
    cosT[i] = cosf(ang); sinT[i] = sinf(ang);
}
__global__ void rope_apply(u16* __restrict__ tq, const float* __restrict__ cosT,
                           const float* __restrict__ sinT) {
    long i = (long)blockIdx.x * 256 + threadIdx.x;
    int j = (int)(i & 255), m = (int)((i >> 8) & 1023);
    float c = cosT[m * 256 + j], s = sinT[m * 256 + j];
    long base = i * 2;
    float te = bf2f(tq[base]), to = bf2f(tq[base + 1]);
    tq[base]     = f2bf(te * c + to * s);
    tq[base + 1] = f2bf(-te * s + to * c);
}
__global__ void transpose_v(const u16* __restrict__ v, u16* __restrict__ vT) {
    __shared__ u16 tile[32][33];
    long zb = (long)blockIdx.z * 524288;
    int mo = blockIdx.x * 32, oo = blockIdx.y * 32;
    int tx = threadIdx.x & 31, ty = threadIdx.x >> 5;
    for (int r = ty; r < 32; r += 8) tile[r][tx] = v[zb + (long)(mo + r) * 512 + oo + tx];
    __syncthreads();
    for (int r = ty; r < 32; r += 8) vT[zb + (long)(oo + r) * 1024 + mo + tx] = tile[tx][r];
}
__launch_bounds__(256)
__global__ void softmax_rows4(u16* __restrict__ sc) {
    int row = blockIdx.x * 4 + (threadIdx.x >> 6);
    int lane = threadIdx.x & 63;
    u16* p = sc + (long)row * 1024 + lane * 16;
    float v[16]; float mx = -1e30f;
    #pragma unroll
    for (int i = 0; i < 16; i++) { v[i] = bf2f(p[i]); mx = fmaxf(mx, v[i]); }
    #pragma unroll
    for (int o = 32; o > 0; o >>= 1) mx = fmaxf(mx, __shfl_xor(mx, o, 64));
    float s = 0.f;
    #pragma unroll
    for (int i = 0; i < 16; i++) { v[i] = expf(v[i] - mx); s += v[i]; }
    #pragma unroll
    for (int o = 32; o > 0; o >>= 1) s += __shfl_xor(s, o, 64);
    float r = 1.0f / s;
    #pragma unroll
    for (int i = 0; i < 16; i++) p[i] = f2bf(v[i] * r);
}
__device__ __forceinline__ void cvt8(const float* __restrict__ s, u16* __restrict__ d) {
    f32x4 a = *(const f32x4*)s, b = *(const f32x4*)(s + 4);
    u16x8 o;
    o[0] = f2bf(a[0]); o[1] = f2bf(a[1]); o[2] = f2bf(a[2]); o[3] = f2bf(a[3]);
    o[4] = f2bf(b[0]); o[5] = f2bf(b[1]); o[6] = f2bf(b[2]); o[7] = f2bf(b[3]);
    *(u16x8*)d = o;
}
__global__ void prep_w(const float* __restrict__ Wq, const float* __restrict__ Wk,
                       const float* __restrict__ Wv, const float* __restrict__ Wo,
                       const float* __restrict__ Wff, const float* __restrict__ Wg,
                       const float* __restrict__ Wl,
                       u16* __restrict__ Wqkvb, u16* __restrict__ Wob,
                       u16* __restrict__ Wffb, u16* __restrict__ Wglb) {
    long i = ((long)blockIdx.x * 256 + threadIdx.x) * 8;  // grid 4480
    if (i < 2097152)      cvt8(Wq + i, Wqkvb + i);
    else if (i < 4194304) cvt8(Wk + (i - 2097152), Wqkvb + i);
    else if (i < 6291456) cvt8(Wv + (i - 4194304), Wqkvb + i);
    else if (i < 8388608) cvt8(Wo + (i - 6291456), Wob + (i - 6291456));
    else if (i < 8650752) cvt8(Wff + (i - 8388608), Wffb + (i - 8388608));
    else if (i < 8912896) cvt8(Wg + (i - 8650752), Wglb + (i - 8650752));
    else                  cvt8(Wl + (i - 8912896), Wglb + 262144 + (i - 8912896));
}
__global__ void convert_f2b(const float* __restrict__ s, u16* __restrict__ d, int n) {
    int i = blockIdx.x * 256 + threadIdx.x;
    if (i < n) d[i] = f2bf(s[i]);
}
__global__ void convert3(const float* __restrict__ a, const float* __restrict__ b,
                         const float* __restrict__ c, u16* __restrict__ d) {
    int i = blockIdx.x * 256 + threadIdx.x;
    const float* s = (i < 262144) ? a : (i < 524288) ? b : c;
    d[i] = f2bf(s[i & 262143]);
}

// ---------------- host ----------------
#define MB 1048576L
extern "C" void kernel_launch(void* const* d_in, const int* in_sizes, int n_in,
                              void* d_out, int out_size, void* d_ws, size_t ws_size,
                              hipStream_t stream) {
    (void)in_sizes; (void)n_in; (void)out_size;
    const float* x    = (const float*)d_in[0];
    const float* scale= (const float*)d_in[1];
    const float* Wq   = (const float*)d_in[2];
    const float* Wk   = (const float*)d_in[3];
    const float* Wv   = (const float*)d_in[4];
    const float* Wo   = (const float*)d_in[5];
    const float* bo   = (const float*)d_in[6];
    const float* Wff  = (const float*)d_in[7];
    const float* bff  = (const float*)d_in[8];
    const float* Wg   = (const float*)d_in[9];
    const float* bg   = (const float*)d_in[10];
    const float* Wl   = (const float*)d_in[11];
    const float* bl   = (const float*)d_in[12];
    const float* beta = (const float*)d_in[13];
    float* out = (float*)d_out;
    char* ws = (char*)d_ws;
    const float sscale = 0.044194173824159216f;  // 1/sqrt(512)

    if (ws_size >= 260000000UL) {
        // ===== tier A (~240 MiB) =====
        u16*   xnb   = (u16*)  (ws);                  //   8 MiB bf16 xn
        u16*   q_all = (u16*)  (ws + 8*MB);           //  64 MiB
        u16*   k_all = (u16*)  (ws + 72*MB);          //  64 MiB (-> Wo partials -> FF scratch)
        u16*   vT_all= (u16*)  (ws + 136*MB);         //  64 MiB (h,b,512,1024)
        u16*   sc    = (u16*)  (ws + 200*MB);         //  32 MiB (2-head expS chunk)
        u16*   Wqkvb = (u16*)  (ws + 200*MB);         //  12 MiB (dead before sc)
        u16*   Wob   = (u16*)  (ws + 232*MB);         //   4 MiB
        u16*   Wffb  = (u16*)  (ws + 236*MB);         //  0.5 MiB
        u16*   Wglb  = (u16*)  (ws + 236*MB + 524288L);   // 1 MiB [Wg;Wl]
        float* csT   = (float*)(ws + 237*MB + 1572864L);  // 2 MiB packed (cos,sin)
        float* rowsum= (float*)(ws + 239*MB + 1572864L);  // 256 KiB
        float* part  = (float*)(ws + 239*MB + 1835008L);  // 2 KiB
        float* x2    = out;                            // 16 MiB fp32 in d_out
        float* wop   = (float*)k_all;                  // Wo split-K partials (64 MiB, k dead)
        u16* x3b = k_all; u16* h1 = k_all + 4194304; u16* g = k_all + 8388608; u16* l = k_all + 12582912;

        sumsq_f32<<<dim3(8, 64), 256, 0, stream>>>(x, part);
        rmsnorm1f_a<<<4096, 256, 0, stream>>>(x, scale, part, bo, xnb, x2);
        rope_tables_a<<<1024, 256, 0, stream>>>(csT, rowsum);
        prep_w<<<4480, 256, 0, stream>>>(Wq, Wk, Wv, Wo, Wff, Wg, Wl,
                                         Wqkvb, Wob, Wffb, Wglb);

        // fused persistent q/k (RoPE) + v (transposed): 1536 tiles on 256 blocks
        gemm256_qkv<<<256, 512, 0, stream>>>(xnb, Wqkvb, q_all, k_all, vT_all, csT);

        // attention: 4 chunks of 2 heads; z = hl*8+b spans contiguous (h,b)
        for (int h0 = 0; h0 < 8; h0 += 2) {
            const long off = (long)h0 * 4194304;
            float* rsc = rowsum + (long)h0 * 8192;
            gemm256<<<dim3(4, 4, 16), 512, 0, stream>>>(q_all + off, k_all + off, 16, 4, 512, 512,
                524288L, 524288L, 512L, 512L, EpiScores{sc, rsc, sscale});
            gemm128<<<dim3(8, 4, 16), 256, 0, stream>>>(sc, vT_all + off, 1024, 1, 1024, 1024,
                1048576L, 524288L, 0L, EpiCtxMul{q_all + off, rsc});
        }
        // cat @ Wo^T: split-K over 4 z-slices -> fp32 partials (no atomics)
        gemm256<<<dim3(32, 2, 4), 512, 0, stream>>>(q_all, Wob, 32, 4, 512, 4096,
            8388608L, 1024L, 4194304L, 512L, EpiPart{wop});
        // x2 += sum partials; fused sumsq
        combine_x2<<<dim3(8, 64), 256, 0, stream>>>(x2, wop, part);
        rmsnorm2_a<<<4096, 256, 0, stream>>>(x2, scale, part, x3b);

        gemm128<<<dim3(64, 4, 1), 256, 0, stream>>>(x3b, Wffb, 512, 1, 512, 512,
            0L, 0L, 0L, EpiBias16{h1, bff});
        gemm128<<<dim3(64, 8, 1), 256, 0, stream>>>(h1, Wglb, 512, 1, 512, 512,
            0L, 0L, 0L, EpiGL{g, l, bg, bl});
        final_out_a<<<4096, 256, 0, stream>>>(x2, scale, part, g, l, beta, out);
        return;
    }

    // ================= tier B/C: per-head loop (<= 86 MiB) =================
    u16*   xnb  = (u16*)  (ws);                  //  8 MiB
    float* x2   = (float*)(ws + 8388608L);       // 16 MiB
    u16*   qh   = (u16*)  (ws + 25165824L);      //  8 MiB
    u16*   kh   = (u16*)  (ws + 33554432L);      //  8 MiB
    u16*   vhc  = (u16*)  (ws + 41943040L);      //  8 MiB v, then ctx
    u16*   vT   = (u16*)  (ws + 50331648L);      //  8 MiB
    u16*   Whb  = (u16*)  (ws + 58720256L);      //  1.5 MiB
    u16*   Wob  = (u16*)  (ws + 60293120L);      //  4 MiB
    u16*   Wfb  = (u16*)  (ws + 64487424L);      //  0.5 MiB
    u16*   Wgb  = (u16*)  (ws + 65011712L);      //  0.5 MiB
    u16*   Wlb  = (u16*)  (ws + 65536000L);      //  0.5 MiB
    float* cosT = (float*)(ws + 66060288L);      //  1 MiB
    float* sinT = (float*)(ws + 67108864L);      //  1 MiB
    float* part = (float*)(ws + 68157440L);
    float* inv1 = (float*)(ws + 68159488L);
    float* inv2 = (float*)(ws + 68159552L);
    u16*   sc   = (u16*)  (ws + 68159616L);      // 16 MiB (big) / 2 MiB (small)
    u16*   x3b = qh;  u16* h1 = kh;  u16* g = vhc;  u16* l = vT;
    const bool big = ws_size >= 85002240UL;

    sumsq_f32<<<dim3(8, 64), 256, 0, stream>>>(x, part);
    finalize_inv<<<8, 64, 0, stream>>>(part, inv1);
    rmsnorm1f<<<16384, 256, 0, stream>>>(x, scale, inv1, bo, xnb, x2);
    rope_tables<<<1024, 256, 0, stream>>>(cosT, sinT);
    convert_f2b<<<8192, 256, 0, stream>>>(Wo, Wob, 2097152);
    convert_f2b<<<1024, 256, 0, stream>>>(Wff, Wfb, 262144);
    convert_f2b<<<1024, 256, 0, stream>>>(Wg, Wgb, 262144);
    convert_f2b<<<1024, 256, 0, stream>>>(Wl, Wlb, 262144);

    for (int h = 0; h < 8; h++) {
        convert3<<<3072, 256, 0, stream>>>(Wq + (long)h * 262144, Wk + (long)h * 262144,
                                           Wv + (long)h * 262144, Whb);
        gemm128<<<dim3(64, 4, 3), 256, 0, stream>>>(xnb, Whb, 512, 1, 512, 512, 0L, 262144L, 0L,
                                                    EpiBF16{qh, 4194304L, 512});
        rope_apply<<<16384, 256, 0, stream>>>(qh, cosT, sinT);   // q and k only
        transpose_v<<<dim3(32, 16, 8), 256, 0, stream>>>(vhc, vT);
        if (big) {
            gemm128<<<dim3(8, 8, 8), 256, 0, stream>>>(qh, kh, 512, 1, 512, 512, 524288L, 524288L,
                                                       0L, EpiScale{sc, 1048576L, 1024, sscale});
            softmax_rows4<<<2048, 256, 0, stream>>>(sc);
            gemm128<<<dim3(8, 4, 8), 256, 0, stream>>>(sc, vT, 1024, 1, 1024, 1024, 1048576L,
                                                       524288L, 0L, EpiBF16{vhc, 524288L, 512});
        } else {
            for (int b = 0; b < 8; b++) {
                gemm128<<<dim3(8, 8, 1), 256, 0, stream>>>(qh + (long)b * 524288, kh + (long)b * 524288,
                                                           512, 1, 512, 512, 0L, 0L, 0L,
                                                           EpiScale{sc, 0L, 1024, sscale});
                softmax_rows4<<<256, 256, 0, stream>>>(sc);
                gemm128<<<dim3(8, 4, 1), 256, 0, stream>>>(sc, vT + (long)b * 524288, 1024, 1, 1024,
                                                           1024, 0L, 0L, 0L,
                                                           EpiBF16{vhc + (long)b * 524288, 0L, 512});
            }
        }
        gemm128<<<dim3(64, 4, 1), 256, 0, stream>>>(vhc, Wob + (long)h * 512, 512, 1, 512, 4096,
                                                    0L, 0L, 0L, EpiAcc{x2});
    }

    sumsq_f32<<<dim3(8, 64), 256, 0, stream>>>(x2, part);
    finalize_inv<<<8, 64, 0, stream>>>(part, inv2);
    rmsnorm2<<<16384, 256, 0, stream>>>(x2, scale, inv2, x3b);
    gemm128<<<dim3(64, 4, 1), 256, 0, stream>>>(x3b, Wfb, 512, 1, 512, 512, 0L, 0L, 0L,
                                                EpiBias16{h1, bff});
    gemm128<<<dim3(64, 4, 1), 256, 0, stream>>>(h1, Wgb, 512, 1, 512, 512, 0L, 0L, 0L,
                                                EpiBias16{g, bg});
    gemm128<<<dim3(64, 4, 1), 256, 0, stream>>>(h1, Wlb, 512, 1, 512, 512, 0L, 0L, 0L,
                                                EpiBias16{l, bl});
    final_out<<<16384, 256, 0, stream>>>(x2, scale, inv2, g, l, beta, out);
}

// Round 6
// 609.618 us; speedup vs baseline: 1.2026x; 1.2026x over previous
//
#include <hip/hip_runtime.h>
#include <math.h>

typedef unsigned short u16;
typedef float f32x2 __attribute__((ext_vector_type(2)));
typedef float f32x4 __attribute__((ext_vector_type(4)));
typedef __bf16 bf16x8 __attribute__((ext_vector_type(8)));
typedef unsigned short u16x4 __attribute__((ext_vector_type(4)));
typedef unsigned short u16x8 __attribute__((ext_vector_type(8)));

__device__ __forceinline__ float bf2f(u16 u) {
    union { float f; unsigned int i; } v; v.i = ((unsigned int)u) << 16; return v.f;
}
__device__ __forceinline__ u16 f2bf(float f) {
    union { float f; unsigned int i; } v; v.f = f;
    unsigned int r = v.i + 0x7fffu + ((v.i >> 16) & 1u);
    return (u16)(r >> 16);
}
// lane^1 value exchange via DPP quad_perm [1,0,3,2] (pure VALU, no LDS pipe)
__device__ __forceinline__ float dpp_swap1(float v) {
    union { float f; int i; } a, b; a.f = v;
    b.i = __builtin_amdgcn_update_dpp(0, a.i, 0xB1, 0xF, 0xF, true);
    return b.f;
}

// async global->LDS, 16B per lane. LDS dest is wave-uniform base + lane*16.
__device__ __forceinline__ void gll(const u16* g, u16* l) {
    __builtin_amdgcn_global_load_lds((const __attribute__((address_space(1))) void*)g,
                                     (__attribute__((address_space(3))) void*)l, 16, 0, 0);
}

// ---------------- epilogue functors (operator() form, for gemm128) ----------------
// r5 LESSON: all-lane scalar epilogues beat half-lane packed ones (latency-bound).
struct EpiBF16 {            // bf16 store with batch stride
    u16* C; long zs; int ldc;
    __device__ void operator()(int z, int m, int n, float v) const {
        C[(long)z * zs + (long)m * ldc + n] = f2bf(v);
    }
};
struct EpiScale {           // scores: scale then bf16 store (tier B/C)
    u16* C; long zs; int ldc; float s;
    __device__ void operator()(int z, int m, int n, float v) const {
        C[(long)z * zs + (long)m * ldc + n] = f2bf(v * s);
    }
};
struct EpiAcc {             // x2 += v  (fp32, 512-wide rows)
    float* x2;
    __device__ void operator()(int z, int m, int n, float v) const {
        x2[(long)m * 512 + n] += v;
    }
};
struct EpiBias16 {          // v + fp32 bias -> bf16
    u16* C; const float* bias;
    __device__ void operator()(int z, int m, int n, float v) const {
        C[(long)m * 512 + n] = f2bf(v + bias[n]);
    }
};
struct EpiGL {              // split N=1024 into g (n<512) and l, with biases
    u16* g; u16* l; const float* bg; const float* bl;
    __device__ void operator()(int z, int m, int n, float v) const {
        if (n < 512) g[(long)m * 512 + n] = f2bf(v + bg[n]);
        else         l[(long)m * 512 + n - 512] = f2bf(v + bl[n - 512]);
    }
};
struct EpiCtxMul {          // ctx: rcp(rowsum) then bf16 store (all lanes, r4 form)
    u16* C; const float* rs;    // rs[z*1024+m] = rowsum
    __device__ void operator()(int z, int m, int n, float v) const {
        float r = __builtin_amdgcn_rcpf(rs[(long)z * 1024 + m]);
        C[(long)z * 524288 + (long)m * 512 + n] = f2bf(v * r);
    }
};

// ---------------- epilogue functors (elem/row form, for gemm256) ----------------
struct EpiScores {          // C = exp(sscale*acc) bf16 (all lanes); rowsum -> atomics
    u16* C; float* rs; float sscale;
    __device__ float elem(int z, int m, int n, float v) const {
        float e = __expf(v * sscale);
        C[(long)z * 1048576 + (long)m * 1024 + n] = f2bf(e);
        return e;
    }
    __device__ void row(int z, int m, float p, int l15) const {
        p += __shfl_xor(p, 1, 64); p += __shfl_xor(p, 2, 64);
        p += __shfl_xor(p, 4, 64); p += __shfl_xor(p, 8, 64);
        if (l15 == 0) atomicAdd(rs + (long)z * 1024 + m, p);
    }
};
struct EpiPart {            // split-K fp32 partials: all-lane plain f32 store
    float* p;               // slice z at z*4194304; adjacent n -> adjacent lanes: coalesced
    __device__ float elem(int z, int m, int n, float v) const {
        p[(long)z * 4194304 + (long)m * 512 + n] = v;
        return 0.f;
    }
    __device__ void row(int, int, float, int) const {}
};

// ======================================================================
// shared 8-phase machinery (gemm256 family)
// ======================================================================
#define RDA(S, I) (*(const bf16x8*)(lds + (S) * 8192 + (I) * 512 + aro))
#define RDB(S, J) (*(const bf16x8*)(lds + (S) * 8192 + (J) * 512 + bro))
#define MFMA_PH(JP) do { \
    __builtin_amdgcn_s_barrier(); \
    asm volatile("s_waitcnt lgkmcnt(0)" ::: "memory"); \
    __builtin_amdgcn_sched_barrier(0); \
    __builtin_amdgcn_s_setprio(1); \
    _Pragma("unroll") \
    for (int i_ = 0; i_ < 8; i_++) { \
        acc[i_][2*(JP)]   = __builtin_amdgcn_mfma_f32_16x16x32_bf16(aF[i_], bF[0], acc[i_][2*(JP)], 0, 0, 0); \
        acc[i_][2*(JP)+1] = __builtin_amdgcn_mfma_f32_16x16x32_bf16(aF[i_], bF[1], acc[i_][2*(JP)+1], 0, 0, 0); \
    } \
    __builtin_amdgcn_s_setprio(0); \
} while (0)

// ======================================================================
// gemm256_qkv: PERSISTENT fused qk+v kernel (r4 form — measured 140 us).
// 1536 tiles (1024 qk + 512 vT), 256 blocks x 6 tiles; 3-half-tile
// stage-ahead crosses tile boundaries so the pipeline never drains.
// qk epilogue: RoPE with DPP partner, ALL 64 lanes, scalar 2B stores.
// ======================================================================
__launch_bounds__(512, 2)
__global__ void gemm256_qkv(const u16* __restrict__ xnb, const u16* __restrict__ Wqkv,
                            u16* __restrict__ q, u16* __restrict__ k, u16* __restrict__ vT,
                            const float* __restrict__ csT) {
    __shared__ __align__(16) u16 lds[65536];
    const int t = threadIdx.x;
    const int lane = t & 63, wave = t >> 6;
    const int wr = wave >> 2, wc = wave & 3;
    const int l15 = lane & 15, quad = lane >> 4;
    const int sr = t >> 2;
    const int scw = ((t & 3) ^ ((t >> 3) & 3)) * 8;
    u16* lA0 = lds + wave * 512 + lane * 8;
    u16* lB0 = lds + 32768 + wave * 512 + lane * 8;
    const int ap = (quad ^ ((l15 >> 1) & 3)) * 8;
    const int aro = (wr * 128 + l15) * 32 + ap;
    const int bro = 32768 + (wc * 64 + l15) * 32 + ap;
    const int bid = blockIdx.x;

    const u16 *curA, *curB, *nxtA, *nxtB;
    int cm0, cn0, cz, cmode, nm0, nn0, nz, nmode;
    auto decode = [&](int tid, const u16*& A_, const u16*& B_,
                      int& m0_, int& n0_, int& z_, int& md_) {
        if (tid > 1535) tid = 1535;
        if (tid < 1024) {               // qk: A=xn rows, B=W rows; z 0..15
            md_ = 0; z_ = tid & 15; int rem = tid >> 4;
            m0_ = (rem >> 1) << 8; n0_ = (rem & 1) << 8;
            A_ = xnb + (long)(m0_ + sr) * 512 + scw;
            B_ = Wqkv + z_ * 262144 + (long)(n0_ + sr) * 512 + scw;
        } else {                        // v transposed: A=Wv, B=xn; z 0..7
            int v = tid - 1024; md_ = 1; z_ = v & 7; int rem = v >> 3;
            m0_ = (rem & 1) << 8; n0_ = (rem >> 1) << 8;
            A_ = Wqkv + 4194304 + z_ * 262144 + (long)(m0_ + sr) * 512 + scw;
            B_ = xnb + (long)(n0_ + sr) * 512 + scw;
        }
    };
    decode(bid, curA, curB, cm0, cn0, cz, cmode);
    decode(bid + 256, nxtA, nxtB, nm0, nn0, nz, nmode);

    auto STGA = [&](int s) {
        const u16* base = (s < 16) ? curA : nxtA;
        int c = (s < 16) ? s : s - 16;
        u16* d = lA0 + (s & 3) * 8192;
        const u16* src = base + c * 32;
        gll(src, d); gll(src + 65536, d + 4096);
    };
    auto STGB = [&](int s) {
        const u16* base = (s < 16) ? curB : nxtB;
        int c = (s < 16) ? s : s - 16;
        u16* d = lB0 + (s & 3) * 8192;
        const u16* src = base + c * 32;
        gll(src, d); gll(src + 65536, d + 4096);
    };

    STGA(0); STGB(0); STGA(1); STGB(1); STGA(2); STGB(2);
    asm volatile("s_waitcnt vmcnt(4)" ::: "memory");
    __builtin_amdgcn_s_barrier();

    for (int j = 0; j < 6; ++j) {
        f32x4 acc[8][4] = {};
        #pragma unroll
        for (int it = 0; it < 4; ++it) {
            const int sh = 3 + it * 4;
            bf16x8 aF[8], bF[2];
            #pragma unroll
            for (int i = 0; i < 8; i++) aF[i] = RDA(0, i);
            bF[0] = RDB(0, 0); bF[1] = RDB(0, 1);
            STGA(sh);
            MFMA_PH(0);
            __builtin_amdgcn_s_barrier();
            bF[0] = RDB(0, 2); bF[1] = RDB(0, 3);
            STGB(sh);
            MFMA_PH(1);
            __builtin_amdgcn_s_barrier();
            #pragma unroll
            for (int i = 0; i < 8; i++) aF[i] = RDA(1, i);
            bF[0] = RDB(1, 0); bF[1] = RDB(1, 1);
            STGA(sh + 1);
            MFMA_PH(0);
            __builtin_amdgcn_s_barrier();
            bF[0] = RDB(1, 2); bF[1] = RDB(1, 3);
            STGB(sh + 1);
            MFMA_PH(1);
            asm volatile("s_waitcnt vmcnt(4)" ::: "memory");
            __builtin_amdgcn_s_barrier();
            #pragma unroll
            for (int i = 0; i < 8; i++) aF[i] = RDA(2, i);
            bF[0] = RDB(2, 0); bF[1] = RDB(2, 1);
            STGA(sh + 2);
            MFMA_PH(0);
            __builtin_amdgcn_s_barrier();
            bF[0] = RDB(2, 2); bF[1] = RDB(2, 3);
            STGB(sh + 2);
            MFMA_PH(1);
            __builtin_amdgcn_s_barrier();
            #pragma unroll
            for (int i = 0; i < 8; i++) aF[i] = RDA(3, i);
            bF[0] = RDB(3, 0); bF[1] = RDB(3, 1);
            STGA(sh + 3);
            MFMA_PH(0);
            __builtin_amdgcn_s_barrier();
            bF[0] = RDB(3, 2); bF[1] = RDB(3, 3);
            STGB(sh + 3);
            MFMA_PH(1);
            asm volatile("s_waitcnt vmcnt(4)" ::: "memory");
            __builtin_amdgcn_s_barrier();
        }
        // ---- epilogue for cur tile (all lanes active; overlaps in-flight loads)
        if (cmode == 0) {
            u16* dst = ((cz >= 8) ? k : q) + ((long)(cz & 7) << 22);
            const int odd = l15 & 1;
            #pragma unroll
            for (int i = 0; i < 8; i++)
                #pragma unroll
                for (int r = 0; r < 4; r++) {
                    int m = cm0 + wr * 128 + i * 16 + quad * 4 + r;
                    const float* cs = csT + (long)(m & 1023) * 512;
                    #pragma unroll
                    for (int jj = 0; jj < 4; jj++) {
                        int n = cn0 + wc * 64 + jj * 16 + l15;
                        float val = acc[i][jj][r];
                        float pv = dpp_swap1(val);
                        float c = cs[(n >> 1) * 2], s = cs[(n >> 1) * 2 + 1];
                        float o = odd ? (val * c - pv * s) : (val * c + pv * s);
                        dst[(long)m * 512 + n] = f2bf(o);
                    }
                }
        } else {
            #pragma unroll
            for (int i = 0; i < 8; i++)
                #pragma unroll
                for (int r = 0; r < 4; r++) {
                    int m = cm0 + wr * 128 + i * 16 + quad * 4 + r;     // feature d
                    #pragma unroll
                    for (int jj = 0; jj < 4; jj++) {
                        int n = cn0 + wc * 64 + jj * 16 + l15;           // token
                        vT[((long)cz << 22) + ((long)(n >> 10) << 19) + ((long)m << 10) + (n & 1023)]
                            = f2bf(acc[i][jj][r]);
                    }
                }
        }
        curA = nxtA; curB = nxtB; cm0 = nm0; cn0 = nn0; cz = nz; cmode = nmode;
        decode(bid + (j + 2) * 256, nxtA, nxtB, nm0, nn0, nz, nmode);
    }
    asm volatile("s_waitcnt vmcnt(0)" ::: "memory");
}

// ======================================================================
// gemm256: generic 256x256 8-phase kernel (scores, Wo split-K)
// ======================================================================
template <class Epi>
__launch_bounds__(512, 2)
__global__ void gemm256(const u16* __restrict__ A, const u16* __restrict__ B,
                        int nkh, int kssh, int lda, int ldb,
                        long aBatch, long bBatch, long aSeg, long bSeg, Epi epi) {
    __shared__ __align__(16) u16 lds[65536];    // 128 KiB: A [4][8192], B at +32768
    const int t = threadIdx.x;
    const int lane = t & 63, wave = t >> 6;
    const int wr = wave >> 2, wc = wave & 3;
    const int l15 = lane & 15, quad = lane >> 4;
    const int m0 = blockIdx.x * 256, n0 = blockIdx.y * 256;
    const int z = blockIdx.z;
    const int sr = t >> 2;                               // 0..127
    const int scw = ((t & 3) ^ ((t >> 3) & 3)) * 8;      // pre-swizzled col block
    const u16* gA = A + (long)z * aBatch + (long)(m0 + sr) * lda + scw;
    const u16* gB = B + (long)z * bBatch + (long)(n0 + sr) * ldb + scw;
    const long a128 = 128L * lda, b128 = 128L * ldb;
    u16* lA0 = lds + wave * 512 + lane * 8;
    u16* lB0 = lds + 32768 + wave * 512 + lane * 8;
    const int kmask = (1 << kssh) - 1;

    auto STA = [&](int shp) {
        int c = shp < nkh ? shp : nkh - 1;               // tail clamp (data unused)
        const u16* s = gA + (long)(c >> kssh) * aSeg + (c & kmask) * 32;
        u16* d = lA0 + (shp & 3) * 8192;
        gll(s, d); gll(s + a128, d + 4096);
    };
    auto STB = [&](int shp) {
        int c = shp < nkh ? shp : nkh - 1;
        const u16* s = gB + (long)(c >> kssh) * bSeg + (c & kmask) * 32;
        u16* d = lB0 + (shp & 3) * 8192;
        gll(s, d); gll(s + b128, d + 4096);
    };

    const int ap = (quad ^ ((l15 >> 1) & 3)) * 8;
    const int aro = (wr * 128 + l15) * 32 + ap;
    const int bro = 32768 + (wc * 64 + l15) * 32 + ap;
    f32x4 acc[8][4] = {};

    STA(0); STB(0); STA(1); STB(1); STA(2); STB(2);
    asm volatile("s_waitcnt vmcnt(4)" ::: "memory");
    __builtin_amdgcn_s_barrier();

    const int niter = nkh >> 2;                          // K/128
    int sh = 3;
    for (int it = 0; it < niter; it++) {
        bf16x8 aF[8], bF[2];
        #pragma unroll
        for (int i = 0; i < 8; i++) aF[i] = RDA(0, i);
        bF[0] = RDB(0, 0); bF[1] = RDB(0, 1);
        STA(sh);
        MFMA_PH(0);
        __builtin_amdgcn_s_barrier();
        bF[0] = RDB(0, 2); bF[1] = RDB(0, 3);
        STB(sh);
        MFMA_PH(1);
        __builtin_amdgcn_s_barrier();
        #pragma unroll
        for (int i = 0; i < 8; i++) aF[i] = RDA(1, i);
        bF[0] = RDB(1, 0); bF[1] = RDB(1, 1);
        STA(sh + 1);
        MFMA_PH(0);
        __builtin_amdgcn_s_barrier();
        bF[0] = RDB(1, 2); bF[1] = RDB(1, 3);
        STB(sh + 1);
        MFMA_PH(1);
        asm volatile("s_waitcnt vmcnt(4)" ::: "memory");
        __builtin_amdgcn_s_barrier();
        #pragma unroll
        for (int i = 0; i < 8; i++) aF[i] = RDA(2, i);
        bF[0] = RDB(2, 0); bF[1] = RDB(2, 1);
        STA(sh + 2);
        MFMA_PH(0);
        __builtin_amdgcn_s_barrier();
        bF[0] = RDB(2, 2); bF[1] = RDB(2, 3);
        STB(sh + 2);
        MFMA_PH(1);
        __builtin_amdgcn_s_barrier();
        #pragma unroll
        for (int i = 0; i < 8; i++) aF[i] = RDA(3, i);
        bF[0] = RDB(3, 0); bF[1] = RDB(3, 1);
        STA(sh + 3);
        MFMA_PH(0);
        __builtin_amdgcn_s_barrier();
        bF[0] = RDB(3, 2); bF[1] = RDB(3, 3);
        STB(sh + 3);
        MFMA_PH(1);
        asm volatile("s_waitcnt vmcnt(4)" ::: "memory");
        __builtin_amdgcn_s_barrier();
        sh += 4;
    }
    asm volatile("s_waitcnt vmcnt(0)" ::: "memory");

    #pragma unroll
    for (int i = 0; i < 8; i++)
        #pragma unroll
        for (int r = 0; r < 4; r++) {
            int m = m0 + wr * 128 + i * 16 + quad * 4 + r;
            float p = 0.f;
            #pragma unroll
            for (int j = 0; j < 4; j++)
                p += epi.elem(z, m, n0 + wc * 64 + j * 16 + l15, acc[i][j][r]);
            epi.row(z, m, p, l15);
        }
}
#undef RDA
#undef RDB
#undef MFMA_PH

// ------- GEMM 128x128 tile, BK=64. 32 KiB LDS -> 4 blocks/CU.
template <class Epi>
__launch_bounds__(256, 4)
__global__ void gemm128(const u16* __restrict__ A, const u16* __restrict__ B,
                        int Kseg, int nSeg, int lda, int ldb,
                        long aBatch, long bBatch, long aSeg, Epi epi) {
    __shared__ __align__(16) u16 sA[8192];   // 128 x 64
    __shared__ __align__(16) u16 sB[8192];
    const int t = threadIdx.x;
    const int lane = t & 63, wave = t >> 6;
    const int wr = wave >> 1, wc = wave & 1;
    const int l15 = lane & 15, quad = lane >> 4;
    const int m0 = blockIdx.x * 128, n0 = blockIdx.y * 128;
    const int sr = t >> 2;
    const int scw = ((t & 3) ^ ((t >> 3) & 3)) * 8;
    const u16* gA = A + (long)blockIdx.z * aBatch + (long)(m0 + sr) * lda + scw;
    const u16* gB = B + (long)blockIdx.z * bBatch + (long)(n0 + sr) * ldb + scw;
    const long a2 = 64L * lda, b2 = 64L * ldb;
    u16* lA = sA + wave * 512 + lane * 8;
    u16* lB = sB + wave * 512 + lane * 8;
    const int ap = (quad ^ ((l15 >> 1) & 3)) * 8;
    const int ab = (wr * 64 + l15) * 32 + ap;
    const int bb = (wc * 64 + l15) * 32 + ap;
    f32x4 acc[4][4] = {};
    for (int s = 0; s < nSeg; s++) {
        const u16* gAs = gA + (long)s * aSeg;
        const u16* gBs = gB + s * Kseg;
        for (int k0 = 0; k0 < Kseg; k0 += 64) {
            gll(gAs + k0, lA);             gll(gAs + k0 + a2, lA + 2048);
            gll(gBs + k0, lB);             gll(gBs + k0 + b2, lB + 2048);
            gll(gAs + k0 + 32, lA + 4096); gll(gAs + k0 + 32 + a2, lA + 6144);
            gll(gBs + k0 + 32, lB + 4096); gll(gBs + k0 + 32 + b2, lB + 6144);
            __syncthreads();
            #pragma unroll
            for (int half = 0; half < 2; half++) {
                bf16x8 aF[4], bF[4];
                #pragma unroll
                for (int i = 0; i < 4; i++) aF[i] = *(const bf16x8*)(sA + half * 4096 + ab + i * 512);
                #pragma unroll
                for (int j = 0; j < 4; j++) bF[j] = *(const bf16x8*)(sB + half * 4096 + bb + j * 512);
                #pragma unroll
                for (int i = 0; i < 4; i++)
                    #pragma unroll
                    for (int j = 0; j < 4; j++)
                        acc[i][j] = __builtin_amdgcn_mfma_f32_16x16x32_bf16(aF[i], bF[j], acc[i][j], 0, 0, 0);
            }
            __syncthreads();
        }
    }
    #pragma unroll
    for (int i = 0; i < 4; i++)
        #pragma unroll
        for (int j = 0; j < 4; j++)
            #pragma unroll
            for (int r = 0; r < 4; r++)
                epi(blockIdx.z, m0 + wr * 64 + i * 16 + quad * 4 + r,
                    n0 + wc * 64 + j * 16 + l15, acc[i][j][r]);
}

// ---------------- reductions / elementwise ----------------
__device__ __forceinline__ float waveSum(float v) {
    #pragma unroll
    for (int o = 32; o > 0; o >>= 1) v += __shfl_down(v, o, 64);
    return v;
}
__device__ __forceinline__ float invFromPart(const float* part, int b) {
    float s = part[b * 64 + (threadIdx.x & 63)];
    s = waveSum(s);
    s = __shfl(s, 0, 64);
    return sqrtf(524288.0f / s);
}

__global__ void sumsq_f32(const float* __restrict__ x, float* __restrict__ part) {
    __shared__ float tmp[4];
    long base = (long)blockIdx.x * 524288 + (long)blockIdx.y * 8192;
    float s = 0.f;
    for (int i = threadIdx.x * 4; i < 8192; i += 1024) {
        f32x4 v = *(const f32x4*)(x + base + i);
        s += v[0] * v[0] + v[1] * v[1] + v[2] * v[2] + v[3] * v[3];
    }
    s = waveSum(s);
    if ((threadIdx.x & 63) == 0) tmp[threadIdx.x >> 6] = s;
    __syncthreads();
    if (threadIdx.x == 0) part[blockIdx.x * 64 + blockIdx.y] = tmp[0] + tmp[1] + tmp[2] + tmp[3];
}
// x2 += sum of 4 Wo split-K partials; fused sumsq of result
__global__ void combine_x2(float* __restrict__ x2, const float* __restrict__ p,
                           float* __restrict__ part) {
    __shared__ float tmp[4];
    long base = (long)blockIdx.x * 524288 + (long)blockIdx.y * 8192;
    float s = 0.f;
    for (int i = threadIdx.x * 4; i < 8192; i += 1024) {
        f32x4 v = *(const f32x4*)(x2 + base + i);
        v = v + *(const f32x4*)(p + base + i);
        v = v + *(const f32x4*)(p + 4194304 + base + i);
        v = v + *(const f32x4*)(p + 8388608 + base + i);
        v = v + *(const f32x4*)(p + 12582912 + base + i);
        *(f32x4*)(x2 + base + i) = v;
        s += v[0] * v[0] + v[1] * v[1] + v[2] * v[2] + v[3] * v[3];
    }
    s = waveSum(s);
    if ((threadIdx.x & 63) == 0) tmp[threadIdx.x >> 6] = s;
    __syncthreads();
    if (threadIdx.x == 0) part[blockIdx.x * 64 + blockIdx.y] = tmp[0] + tmp[1] + tmp[2] + tmp[3];
}
__global__ void finalize_inv(const float* __restrict__ part, float* __restrict__ inv) {
    float s = part[blockIdx.x * 64 + threadIdx.x];
    s = waveSum(s);
    if (threadIdx.x == 0) inv[blockIdx.x] = sqrtf(524288.0f / s);  // 1/ff_rms
}
// tier A vectorized (x4) elementwise
__global__ void rmsnorm1f_a(const float* __restrict__ x, const float* __restrict__ scale,
                            const float* __restrict__ part, const float* __restrict__ bo,
                            u16* __restrict__ xnb, float* __restrict__ x2) {
    long i = ((long)blockIdx.x * 256 + threadIdx.x) * 4;     // grid 4096
    int b = (int)(i >> 19);
    float inv = invFromPart(part, b);
    f32x4 xv = *(const f32x4*)(x + i);
    f32x4 sv = *(const f32x4*)(scale + (int)(i & 524287));
    f32x4 bv = *(const f32x4*)(bo + (int)(i & 511));
    f32x4 v; u16x4 o;
    #pragma unroll
    for (int j = 0; j < 4; j++) { v[j] = xv[j] * inv * sv[j]; o[j] = f2bf(v[j]); }
    *(u16x4*)(xnb + i) = o;
    *(f32x4*)(x2 + i) = v + bv;
}
__global__ void rmsnorm2_a(const float* __restrict__ x2, const float* __restrict__ scale,
                           const float* __restrict__ part, u16* __restrict__ x3b) {
    long i = ((long)blockIdx.x * 256 + threadIdx.x) * 4;
    int b = (int)(i >> 19);
    float inv = invFromPart(part, b);
    f32x4 xv = *(const f32x4*)(x2 + i);
    f32x4 sv = *(const f32x4*)(scale + (int)(i & 524287));
    u16x4 o;
    #pragma unroll
    for (int j = 0; j < 4; j++) o[j] = f2bf(xv[j] * inv * sv[j]);
    *(u16x4*)(x3b + i) = o;
}
__global__ void final_out_a(const float* __restrict__ x2, const float* __restrict__ scale,
                            const float* __restrict__ part, const u16* __restrict__ g,
                            const u16* __restrict__ l, const float* __restrict__ beta,
                            float* __restrict__ out) {
    long i = ((long)blockIdx.x * 256 + threadIdx.x) * 4;
    int b = (int)(i >> 19);
    float inv2 = invFromPart(part, b);
    float bta = beta[0];
    f32x4 xv = *(const f32x4*)(x2 + i);
    f32x4 sv = *(const f32x4*)(scale + (int)(i & 524287));
    u16x4 gv4 = *(const u16x4*)(g + i);
    u16x4 lv4 = *(const u16x4*)(l + i);
    f32x4 o;
    #pragma unroll
    for (int j = 0; j < 4; j++) {
        float x3 = xv[j] * inv2 * sv[j];
        float gv = bf2f(gv4[j]), lv = bf2f(lv4[j]);
        float sw = gv / (1.0f + __expf(-bta * gv));
        o[j] = x3 + sw * lv;
    }
    *(f32x4*)(out + i) = o;
}
// tier B/C versions
__global__ void rmsnorm1f(const float* __restrict__ x, const float* __restrict__ scale,
                          const float* __restrict__ inv, const float* __restrict__ bo,
                          u16* __restrict__ xnb, float* __restrict__ x2) {
    long i = (long)blockIdx.x * 256 + threadIdx.x;
    int b = (int)(i >> 19), md = (int)(i & 524287);
    float v = x[i] * inv[b] * scale[md];
    xnb[i] = f2bf(v);
    x2[i] = v + bo[i & 511];
}
__global__ void rmsnorm2(const float* __restrict__ x2, const float* __restrict__ scale,
                         const float* __restrict__ inv, u16* __restrict__ x3b) {
    long i = (long)blockIdx.x * 256 + threadIdx.x;
    int b = (int)(i >> 19), md = (int)(i & 524287);
    x3b[i] = f2bf(x2[i] * inv[b] * scale[md]);
}
__global__ void final_out(const float* __restrict__ x2, const float* __restrict__ scale,
                          const float* __restrict__ inv2, const u16* __restrict__ g,
                          const u16* __restrict__ l, const float* __restrict__ beta,
                          float* __restrict__ out) {
    long i = (long)blockIdx.x * 256 + threadIdx.x;
    int b = (int)(i >> 19), md = (int)(i & 524287);
    float x3 = x2[i] * inv2[b] * scale[md];
    float gv = bf2f(g[i]), lv = bf2f(l[i]);
    float bta = beta[0];
    float sw = gv / (1.0f + expf(-bta * gv));
    out[i] = x3 + sw * lv;
}
__global__ void rope_tables_a(float* __restrict__ csT, float* __restrict__ rowsum) {
    int i = blockIdx.x * 256 + threadIdx.x;      // 262144
    int m = i >> 8, j = i & 255;
    float theta = powf(10000.0f, -2.0f * ((float)j - 1.0f) / 512.0f);
    float ang = (float)m * theta;
    csT[2 * i] = cosf(ang); csT[2 * i + 1] = sinf(ang);
    if (i < 65536) rowsum[i] = 0.f;
}
__global__ void rope_tables(float* __restrict__ cosT, float* __restrict__ sinT) {
    int i = blockIdx.x * 256 + threadIdx.x;      // 1024*256
    int m = i >> 8, j = i & 255;
    float theta = powf(10000.0f, -2.0f * ((float)j - 1.0f) / 512.0f);
    float ang = (float)m * theta;
    cosT[i] = cosf(ang); sinT[i] = sinf(ang);
}
__global__ void rope_apply(u16* __restrict__ tq, const float* __restrict__ cosT,
                           const float* __restrict__ sinT) {
    long i = (long)blockIdx.x * 256 + threadIdx.x;
    int j = (int)(i & 255), m = (int)((i >> 8) & 1023);
    float c = cosT[m * 256 + j], s = sinT[m * 256 + j];
    long base = i * 2;
    float te = bf2f(tq[base]), to = bf2f(tq[base + 1]);
    tq[base]     = f2bf(te * c + to * s);
    tq[base + 1] = f2bf(-te * s + to * c);
}
__global__ void transpose_v(const u16* __restrict__ v, u16* __restrict__ vT) {
    __shared__ u16 tile[32][33];
    long zb = (long)blockIdx.z * 524288;
    int mo = blockIdx.x * 32, oo = blockIdx.y * 32;
    int tx = threadIdx.x & 31, ty = threadIdx.x >> 5;
    for (int r = ty; r < 32; r += 8) tile[r][tx] = v[zb + (long)(mo + r) * 512 + oo + tx];
    __syncthreads();
    for (int r = ty; r < 32; r += 8) vT[zb + (long)(oo + r) * 1024 + mo + tx] = tile[tx][r];
}
__launch_bounds__(256)
__global__ void softmax_rows4(u16* __restrict__ sc) {
    int row = blockIdx.x * 4 + (threadIdx.x >> 6);
    int lane = threadIdx.x & 63;
    u16* p = sc + (long)row * 1024 + lane * 16;
    float v[16]; float mx = -1e30f;
    #pragma unroll
    for (int i = 0; i < 16; i++) { v[i] = bf2f(p[i]); mx = fmaxf(mx, v[i]); }
    #pragma unroll
    for (int o = 32; o > 0; o >>= 1) mx = fmaxf(mx, __shfl_xor(mx, o, 64));
    float s = 0.f;
    #pragma unroll
    for (int i = 0; i < 16; i++) { v[i] = expf(v[i] - mx); s += v[i]; }
    #pragma unroll
    for (int o = 32; o > 0; o >>= 1) s += __shfl_xor(s, o, 64);
    float r = 1.0f / s;
    #pragma unroll
    for (int i = 0; i < 16; i++) p[i] = f2bf(v[i] * r);
}
__device__ __forceinline__ void cvt8(const float* __restrict__ s, u16* __restrict__ d) {
    f32x4 a = *(const f32x4*)s, b = *(const f32x4*)(s + 4);
    u16x8 o;
    o[0] = f2bf(a[0]); o[1] = f2bf(a[1]); o[2] = f2bf(a[2]); o[3] = f2bf(a[3]);
    o[4] = f2bf(b[0]); o[5] = f2bf(b[1]); o[6] = f2bf(b[2]); o[7] = f2bf(b[3]);
    *(u16x8*)d = o;
}
__global__ void prep_w(const float* __restrict__ Wq, const float* __restrict__ Wk,
                       const float* __restrict__ Wv, const float* __restrict__ Wo,
                       const float* __restrict__ Wff, const float* __restrict__ Wg,
                       const float* __restrict__ Wl,
                       u16* __restrict__ Wqkvb, u16* __restrict__ Wob,
                       u16* __restrict__ Wffb, u16* __restrict__ Wglb) {
    long i = ((long)blockIdx.x * 256 + threadIdx.x) * 8;  // grid 4480
    if (i < 2097152)      cvt8(Wq + i, Wqkvb + i);
    else if (i < 4194304) cvt8(Wk + (i - 2097152), Wqkvb + i);
    else if (i < 6291456) cvt8(Wv + (i - 4194304), Wqkvb + i);
    else if (i < 8388608) cvt8(Wo + (i - 6291456), Wob + (i - 6291456));
    else if (i < 8650752) cvt8(Wff + (i - 8388608), Wffb + (i - 8388608));
    else if (i < 8912896) cvt8(Wg + (i - 8650752), Wglb + (i - 8650752));
    else                  cvt8(Wl + (i - 8912896), Wglb + 262144 + (i - 8912896));
}
__global__ void convert_f2b(const float* __restrict__ s, u16* __restrict__ d, int n) {
    int i = blockIdx.x * 256 + threadIdx.x;
    if (i < n) d[i] = f2bf(s[i]);
}
__global__ void convert3(const float* __restrict__ a, const float* __restrict__ b,
                         const float* __restrict__ c, u16* __restrict__ d) {
    int i = blockIdx.x * 256 + threadIdx.x;
    const float* s = (i < 262144) ? a : (i < 524288) ? b : c;
    d[i] = f2bf(s[i & 262143]);
}

// ---------------- host ----------------
#define MB 1048576L
extern "C" void kernel_launch(void* const* d_in, const int* in_sizes, int n_in,
                              void* d_out, int out_size, void* d_ws, size_t ws_size,
                              hipStream_t stream) {
    (void)in_sizes; (void)n_in; (void)out_size;
    const float* x    = (const float*)d_in[0];
    const float* scale= (const float*)d_in[1];
    const float* Wq   = (const float*)d_in[2];
    const float* Wk   = (const float*)d_in[3];
    const float* Wv   = (const float*)d_in[4];
    const float* Wo   = (const float*)d_in[5];
    const float* bo   = (const float*)d_in[6];
    const float* Wff  = (const float*)d_in[7];
    const float* bff  = (const float*)d_in[8];
    const float* Wg   = (const float*)d_in[9];
    const float* bg   = (const float*)d_in[10];
    const float* Wl   = (const float*)d_in[11];
    const float* bl   = (const float*)d_in[12];
    const float* beta = (const float*)d_in[13];
    float* out = (float*)d_out;
    char* ws = (char*)d_ws;
    const float sscale = 0.044194173824159216f;  // 1/sqrt(512)

    if (ws_size >= 260000000UL) {
        // ===== tier A (~240 MiB) =====
        u16*   xnb   = (u16*)  (ws);                  //   8 MiB bf16 xn
        u16*   q_all = (u16*)  (ws + 8*MB);           //  64 MiB
        u16*   k_all = (u16*)  (ws + 72*MB);          //  64 MiB (-> Wo partials -> FF scratch)
        u16*   vT_all= (u16*)  (ws + 136*MB);         //  64 MiB (h,b,512,1024)
        u16*   sc    = (u16*)  (ws + 200*MB);         //  32 MiB (2-head expS chunk)
        u16*   Wqkvb = (u16*)  (ws + 200*MB);         //  12 MiB (dead before sc)
        u16*   Wob   = (u16*)  (ws + 232*MB);         //   4 MiB
        u16*   Wffb  = (u16*)  (ws + 236*MB);         //  0.5 MiB
        u16*   Wglb  = (u16*)  (ws + 236*MB + 524288L);   // 1 MiB [Wg;Wl]
        float* csT   = (float*)(ws + 237*MB + 1572864L);  // 2 MiB packed (cos,sin)
        float* rowsum= (float*)(ws + 239*MB + 1572864L);  // 256 KiB
        float* part  = (float*)(ws + 239*MB + 1835008L);  // 2 KiB
        float* x2    = out;                            // 16 MiB fp32 in d_out
        float* wop   = (float*)k_all;                  // Wo split-K partials (64 MiB, k dead)
        u16* x3b = k_all; u16* h1 = k_all + 4194304; u16* g = k_all + 8388608; u16* l = k_all + 12582912;

        sumsq_f32<<<dim3(8, 64), 256, 0, stream>>>(x, part);
        rmsnorm1f_a<<<4096, 256, 0, stream>>>(x, scale, part, bo, xnb, x2);
        rope_tables_a<<<1024, 256, 0, stream>>>(csT, rowsum);
        prep_w<<<4480, 256, 0, stream>>>(Wq, Wk, Wv, Wo, Wff, Wg, Wl,
                                         Wqkvb, Wob, Wffb, Wglb);

        // fused persistent q/k (RoPE) + v (transposed): 1536 tiles on 256 blocks
        gemm256_qkv<<<256, 512, 0, stream>>>(xnb, Wqkvb, q_all, k_all, vT_all, csT);

        // attention: 4 chunks of 2 heads; z = hl*8+b spans contiguous (h,b)
        for (int h0 = 0; h0 < 8; h0 += 2) {
            const long off = (long)h0 * 4194304;
            float* rsc = rowsum + (long)h0 * 8192;
            gemm256<<<dim3(4, 4, 16), 512, 0, stream>>>(q_all + off, k_all + off, 16, 4, 512, 512,
                524288L, 524288L, 512L, 512L, EpiScores{sc, rsc, sscale});
            gemm128<<<dim3(8, 4, 16), 256, 0, stream>>>(sc, vT_all + off, 1024, 1, 1024, 1024,
                1048576L, 524288L, 0L, EpiCtxMul{q_all + off, rsc});
        }
        // cat @ Wo^T: split-K over 4 z-slices -> fp32 partials (no atomics)
        gemm256<<<dim3(32, 2, 4), 512, 0, stream>>>(q_all, Wob, 32, 4, 512, 4096,
            8388608L, 1024L, 4194304L, 512L, EpiPart{wop});
        // x2 += sum partials; fused sumsq
        combine_x2<<<dim3(8, 64), 256, 0, stream>>>(x2, wop, part);
        rmsnorm2_a<<<4096, 256, 0, stream>>>(x2, scale, part, x3b);

        gemm128<<<dim3(64, 4, 1), 256, 0, stream>>>(x3b, Wffb, 512, 1, 512, 512,
            0L, 0L, 0L, EpiBias16{h1, bff});
        gemm128<<<dim3(64, 8, 1), 256, 0, stream>>>(h1, Wglb, 512, 1, 512, 512,
            0L, 0L, 0L, EpiGL{g, l, bg, bl});
        final_out_a<<<4096, 256, 0, stream>>>(x2, scale, part, g, l, beta, out);
        return;
    }

    // ================= tier B/C: per-head loop (<= 86 MiB) =================
    u16*   xnb  = (u16*)  (ws);                  //  8 MiB
    float* x2   = (float*)(ws + 8388608L);       // 16 MiB
    u16*   qh   = (u16*)  (ws + 25165824L);      //  8 MiB
    u16*   kh   = (u16*)  (ws + 33554432L);      //  8 MiB
    u16*   vhc  = (u16*)  (ws + 41943040L);      //  8 MiB v, then ctx
    u16*   vT   = (u16*)  (ws + 50331648L);      //  8 MiB
    u16*   Whb  = (u16*)  (ws + 58720256L);      //  1.5 MiB
    u16*   Wob  = (u16*)  (ws + 60293120L);      //  4 MiB
    u16*   Wfb  = (u16*)  (ws + 64487424L);      //  0.5 MiB
    u16*   Wgb  = (u16*)  (ws + 65011712L);      //  0.5 MiB
    u16*   Wlb  = (u16*)  (ws + 65536000L);      //  0.5 MiB
    float* cosT = (float*)(ws + 66060288L);      //  1 MiB
    float* sinT = (float*)(ws + 67108864L);      //  1 MiB
    float* part = (float*)(ws + 68157440L);
    float* inv1 = (float*)(ws + 68159488L);
    float* inv2 = (float*)(ws + 68159552L);
    u16*   sc   = (u16*)  (ws + 68159616L);      // 16 MiB (big) / 2 MiB (small)
    u16*   x3b = qh;  u16* h1 = kh;  u16* g = vhc;  u16* l = vT;
    const bool big = ws_size >= 85002240UL;

    sumsq_f32<<<dim3(8, 64), 256, 0, stream>>>(x, part);
    finalize_inv<<<8, 64, 0, stream>>>(part, inv1);
    rmsnorm1f<<<16384, 256, 0, stream>>>(x, scale, inv1, bo, xnb, x2);
    rope_tables<<<1024, 256, 0, stream>>>(cosT, sinT);
    convert_f2b<<<8192, 256, 0, stream>>>(Wo, Wob, 2097152);
    convert_f2b<<<1024, 256, 0, stream>>>(Wff, Wfb, 262144);
    convert_f2b<<<1024, 256, 0, stream>>>(Wg, Wgb, 262144);
    convert_f2b<<<1024, 256, 0, stream>>>(Wl, Wlb, 262144);

    for (int h = 0; h < 8; h++) {
        convert3<<<3072, 256, 0, stream>>>(Wq + (long)h * 262144, Wk + (long)h * 262144,
                                           Wv + (long)h * 262144, Whb);
        gemm128<<<dim3(64, 4, 3), 256, 0, stream>>>(xnb, Whb, 512, 1, 512, 512, 0L, 262144L, 0L,
                                                    EpiBF16{qh, 4194304L, 512});
        rope_apply<<<16384, 256, 0, stream>>>(qh, cosT, sinT);   // q and k only
        transpose_v<<<dim3(32, 16, 8), 256, 0, stream>>>(vhc, vT);
        if (big) {
            gemm128<<<dim3(8, 8, 8), 256, 0, stream>>>(qh, kh, 512, 1, 512, 512, 524288L, 524288L,
                                                       0L, EpiScale{sc, 1048576L, 1024, sscale});
            softmax_rows4<<<2048, 256, 0, stream>>>(sc);
            gemm128<<<dim3(8, 4, 8), 256, 0, stream>>>(sc, vT, 1024, 1, 1024, 1024, 1048576L,
                                                       524288L, 0L, EpiBF16{vhc, 524288L, 512});
        } else {
            for (int b = 0; b < 8; b++) {
                gemm128<<<dim3(8, 8, 1), 256, 0, stream>>>(qh + (long)b * 524288, kh + (long)b * 524288,
                                                           512, 1, 512, 512, 0L, 0L, 0L,
                                                           EpiScale{sc, 0L, 1024, sscale});
                softmax_rows4<<<256, 256, 0, stream>>>(sc);
                gemm128<<<dim3(8, 4, 1), 256, 0, stream>>>(sc, vT + (long)b * 524288, 1024, 1, 1024,
                                                           1024, 0L, 0L, 0L,
                                                           EpiBF16{vhc + (long)b * 524288, 0L, 512});
            }
        }
        gemm128<<<dim3(64, 4, 1), 256, 0, stream>>>(vhc, Wob + (long)h * 512, 512, 1, 512, 4096,
                                                    0L, 0L, 0L, EpiAcc{x2});
    }

    sumsq_f32<<<dim3(8, 64), 256, 0, stream>>>(x2, part);
    finalize_inv<<<8, 64, 0, stream>>>(part, inv2);
    rmsnorm2<<<16384, 256, 0, stream>>>(x2, scale, inv2, x3b);
    gemm128<<<dim3(64, 4, 1), 256, 0, stream>>>(x3b, Wfb, 512, 1, 512, 512, 0L, 0L, 0L,
                                                EpiBias16{h1, bff});
    gemm128<<<dim3(64, 4, 1), 256, 0, stream>>>(h1, Wgb, 512, 1, 512, 512, 0L, 0L, 0L,
                                                EpiBias16{g, bg});
    gemm128<<<dim3(64, 4, 1), 256, 0, stream>>>(h1, Wlb, 512, 1, 512, 512, 0L, 0L, 0L,
                                                EpiBias16{l, bl});
    final_out<<<16384, 256, 0, stream>>>(x2, scale, inv2, g, l, beta, out);
}